// Round 13
// baseline (1530.867 us; speedup 1.0000x reference)
//
#include <hip/hip_runtime.h>
#include <hip/hip_cooperative_groups.h>
#include <hip/hip_bf16.h>
#include <math.h>

namespace cg = cooperative_groups;

// ---------------------------------------------------------------------------
// Generalised gated MoE U-net, B=2048, E=4, W=10, fp32 throughout.
// Round 13: ONE cooperative kernel, 19 phases with grid.sync() between.
//   Kills ~170us of launch/drain bubbles across the 22-dispatch chain.
//   Conv phase bodies = R12's proven kernels. Gate finalize precomputed
//   (redundant colsum per block, once per layer) -> convs ld4 gate[b].
//   Conv5 writes 5 partial-1x1 slices; final phase sums them (no atomics).
//   Grid sized by occupancy query (no deadlock; phases are vb-strided).
// ---------------------------------------------------------------------------

constexpr int BATCH = 2048;

// ---------------- workspace layout (floats) ----------------
constexpr size_t PADF    = 1024;
constexpr size_t F_CONV1 = (size_t)BATCH * 10 * 784;   // 16,056,320
constexpr size_t F_XPAD  = (size_t)BATCH * 784;
constexpr size_t F_P1    = (size_t)BATCH * 10 * 196;
constexpr size_t F_CONV2 = F_P1;
constexpr size_t F_P2    = (size_t)BATCH * 10 * 49;
constexpr size_t F_CONV3 = (size_t)BATCH * 20 * 49;
constexpr size_t F_UP3   = (size_t)BATCH * 20 * 196;
constexpr size_t F_M4    = F_P1;
constexpr size_t F_UP4   = F_CONV1;
constexpr size_t F_M5P   = (size_t)5 * BATCH * 784;    // 5 partial slices

constexpr size_t O_CONV1 = PADF;
constexpr size_t O_Z2    = O_CONV1 + F_CONV1 + PADF;
constexpr size_t O_XPAD  = O_Z2;
constexpr size_t O_P1    = O_XPAD + F_XPAD + PADF;
constexpr size_t O_CONV2 = O_P1 + F_P1 + PADF;
constexpr size_t O_P2    = O_CONV2 + F_CONV2 + PADF;
constexpr size_t O_CONV3 = O_P2 + F_P2 + PADF;
constexpr size_t O_UP3   = O_CONV3 + F_CONV3 + PADF;
constexpr size_t O_M4    = O_UP3 + F_UP3 + PADF;       // beyond up4 extent
constexpr size_t O_UP4   = O_Z2;                       // overlays xpad..up3[:] (dead at P14)
constexpr size_t O_M5P   = O_Z2 + F_UP4 + PADF;        // overlays up3-tail/m4 (dead at P17)
constexpr size_t O_GRAW  = O_M4 + F_M4 + PADF;         // max(m4,m5p) end
constexpr size_t O_GATE  = O_GRAW + 5 * (size_t)BATCH * 4 + PADF;

__device__ __forceinline__ float softplusf(float z) {
    return fmaxf(z, 0.0f) + log1pf(expf(-fabsf(z)));
}
__device__ __forceinline__ float4 ld4(const float* p) { return *(const float4*)p; }

struct Params {
    const float* x;
    const float* cw[5]; const float* cb[5];
    const float* gw[5]; const float* gb[5];
    const float* nw[5]; const float* nb[5];
    const float* eps[5];
    const int*   kp;
    const float* wlast; const float* blast;
    float* out;
    float* conv1; float* xpad; float* p1; float* conv2; float* p2;
    float* conv3; float* up3; float* m4; float* up4; float* m5p;
    float* graw; float* gate;   // [5][BATCH][4] each
};

// shared scratch (one block's worth, reused across phases; barriers guard reuse)
__shared__ __align__(16) float wlds[2176];   // 8704 B: CIN=30 weights
__shared__ float sred[4][16];

// ---------------- gate (2 samples per virtual block) -----------------------
template <int C1HW, int C2HW>
__device__ __forceinline__ void dev_gate_v4(
    const float* __restrict__ x1, const float* __restrict__ x2,
    const float* __restrict__ gw, const float* __restrict__ gb,
    const float* __restrict__ nw, const float* __restrict__ nb,
    const float* __restrict__ eps, float* __restrict__ graw, int vb, int tid)
{
    constexpr int DV = (C1HW + C2HW) / 4;
    const int b0 = vb * 2;
    float ga[2][4] = {}, na[2][4] = {};
    for (int g = tid; g < DV; g += 256) {
        const int d = g * 4;
        float4 xv[2];
        #pragma unroll
        for (int ss = 0; ss < 2; ++ss) {
            const int b = b0 + ss;
            if constexpr (C2HW > 0) {
                xv[ss] = (d < C1HW) ? ld4(x1 + (size_t)b * C1HW + d)
                                    : ld4(x2 + (size_t)b * C2HW + (d - C1HW));
            } else {
                xv[ss] = ld4(x1 + (size_t)b * C1HW + d);
            }
        }
        #pragma unroll
        for (int j = 0; j < 4; ++j) {
            const float4 gv = ((const float4*)gw)[d + j];
            const float4 nv = ((const float4*)nw)[d + j];
            #pragma unroll
            for (int ss = 0; ss < 2; ++ss) {
                const float val = (&xv[ss].x)[j];
                ga[ss][0] = fmaf(val, gv.x, ga[ss][0]);
                ga[ss][1] = fmaf(val, gv.y, ga[ss][1]);
                ga[ss][2] = fmaf(val, gv.z, ga[ss][2]);
                ga[ss][3] = fmaf(val, gv.w, ga[ss][3]);
                na[ss][0] = fmaf(val, nv.x, na[ss][0]);
                na[ss][1] = fmaf(val, nv.y, na[ss][1]);
                na[ss][2] = fmaf(val, nv.z, na[ss][2]);
                na[ss][3] = fmaf(val, nv.w, na[ss][3]);
            }
        }
    }
    #pragma unroll
    for (int m = 32; m >= 1; m >>= 1) {
        #pragma unroll
        for (int ss = 0; ss < 2; ++ss)
            #pragma unroll
            for (int e = 0; e < 4; ++e) {
                ga[ss][e] += __shfl_xor(ga[ss][e], m, 64);
                na[ss][e] += __shfl_xor(na[ss][e], m, 64);
            }
    }
    __syncthreads();                 // guard sred reuse across vb iterations
    const int wave = tid >> 6, lane = tid & 63;
    if (lane == 0) {
        #pragma unroll
        for (int ss = 0; ss < 2; ++ss)
            #pragma unroll
            for (int e = 0; e < 4; ++e) {
                sred[wave][ss * 8 + e]     = ga[ss][e];
                sred[wave][ss * 8 + 4 + e] = na[ss][e];
            }
    }
    __syncthreads();
    if (tid < 2) {
        const int ss = tid;
        #pragma unroll
        for (int e = 0; e < 4; ++e) {
            const float G = sred[0][ss*8+e] + sred[1][ss*8+e]
                          + sred[2][ss*8+e] + sred[3][ss*8+e];
            const float N = sred[0][ss*8+4+e] + sred[1][ss*8+4+e]
                          + sred[2][ss*8+4+e] + sred[3][ss*8+4+e];
            graw[(b0 + ss) * 4 + e] = G + gb[e] + eps[e] * softplusf(N + nb[e]);
        }
    }
}

// scalar gate (D=490), one sample per virtual block
template <int D>
__device__ __forceinline__ void dev_gate_s(
    const float* __restrict__ x1,
    const float* __restrict__ gw, const float* __restrict__ gb,
    const float* __restrict__ nw, const float* __restrict__ nb,
    const float* __restrict__ eps, float* __restrict__ graw, int vb, int tid)
{
    const int b = vb;
    float ga0=0,ga1=0,ga2=0,ga3=0,na0=0,na1=0,na2=0,na3=0;
    for (int d = tid; d < D; d += 256) {
        const float val = x1[(size_t)b * D + d];
        const float4 gv = ((const float4*)gw)[d];
        const float4 nv = ((const float4*)nw)[d];
        ga0 = fmaf(val, gv.x, ga0); ga1 = fmaf(val, gv.y, ga1);
        ga2 = fmaf(val, gv.z, ga2); ga3 = fmaf(val, gv.w, ga3);
        na0 = fmaf(val, nv.x, na0); na1 = fmaf(val, nv.y, na1);
        na2 = fmaf(val, nv.z, na2); na3 = fmaf(val, nv.w, na3);
    }
    #pragma unroll
    for (int m = 32; m >= 1; m >>= 1) {
        ga0 += __shfl_xor(ga0, m, 64); ga1 += __shfl_xor(ga1, m, 64);
        ga2 += __shfl_xor(ga2, m, 64); ga3 += __shfl_xor(ga3, m, 64);
        na0 += __shfl_xor(na0, m, 64); na1 += __shfl_xor(na1, m, 64);
        na2 += __shfl_xor(na2, m, 64); na3 += __shfl_xor(na3, m, 64);
    }
    __syncthreads();
    const int wave = tid >> 6, lane = tid & 63;
    if (lane == 0) {
        sred[wave][0] = ga0; sred[wave][1] = ga1; sred[wave][2] = ga2; sred[wave][3] = ga3;
        sred[wave][4] = na0; sred[wave][5] = na1; sred[wave][6] = na2; sred[wave][7] = na3;
    }
    __syncthreads();
    if (tid == 0) {
        #pragma unroll
        for (int e = 0; e < 4; ++e) {
            const float G = sred[0][e]+sred[1][e]+sred[2][e]+sred[3][e];
            const float N = sred[0][4+e]+sred[1][4+e]+sred[2][4+e]+sred[3][4+e];
            graw[b * 4 + e] = G + gb[e] + eps[e] * softplusf(N + nb[e]);
        }
    }
}

// ---------------- finalize: redundant colsum + per-sample softmax ----------
__device__ __forceinline__ void dev_finalize(
    const float* __restrict__ graw, const int* __restrict__ kp,
    float* __restrict__ gate, int tid, int nb)
{
    float a0=0,a1=0,a2=0,a3=0;
    for (int i = tid; i < BATCH; i += 256) {
        const float4 v = ld4(graw + i * 4);
        a0 += v.x; a1 += v.y; a2 += v.z; a3 += v.w;
    }
    #pragma unroll
    for (int m = 32; m >= 1; m >>= 1) {
        a0 += __shfl_xor(a0, m, 64); a1 += __shfl_xor(a1, m, 64);
        a2 += __shfl_xor(a2, m, 64); a3 += __shfl_xor(a3, m, 64);
    }
    __syncthreads();
    const int wave = tid >> 6, lane = tid & 63;
    if (lane == 0) {
        sred[wave][0] = a0; sred[wave][1] = a1; sred[wave][2] = a2; sred[wave][3] = a3;
    }
    __syncthreads();
    float cs[4];
    #pragma unroll
    for (int e = 0; e < 4; ++e)
        cs[e] = sred[0][e] + sred[1][e] + sred[2][e] + sred[3][e];

    int k = kp[0];
    k = (k < 1) ? 1 : (k > 4 ? 4 : k);
    bool sel[4] = {false, false, false, false};
    for (int it = 0; it < k; ++it) {
        int bi = 0; float bv = -INFINITY;
        #pragma unroll
        for (int e = 0; e < 4; ++e)
            if (!sel[e] && cs[e] > bv) { bv = cs[e]; bi = e; }
        sel[bi] = true;
    }
    for (int b = blockIdx.x * 256 + tid; b < BATCH; b += nb * 256) {
        float g[4];
        #pragma unroll
        for (int e = 0; e < 4; ++e) {
            const float v = graw[b * 4 + e];
            g[e] = sel[e] ? v : 0.0f;       // zero BEFORE softmax (reference)
        }
        const float mx = fmaxf(fmaxf(g[0], g[1]), fmaxf(g[2], g[3]));
        const float e0 = expf(g[0]-mx), e1 = expf(g[1]-mx);
        const float e2 = expf(g[2]-mx), e3 = expf(g[3]-mx);
        const float inv = 1.0f / (e0 + e1 + e2 + e3);
        float4 o = {e0*inv, e1*inv, e2*inv, e3*inv};
        *(float4*)(gate + b * 4) = o;
    }
}

// ---------------- quad conv (2-row x 4-col; 28x28 layers) -------------------
// PARTIAL=1: write 1x1-partial slice (s0*wl[c0] + s1*wl[c0+1]) to out.
template <int CIN1, int CIN2, int COUT, int POOL, int PARTIAL>
__device__ __forceinline__ void dev_conv_q4(
    const float* __restrict__ x1, const float* __restrict__ x2,
    const float* __restrict__ cw, const float* __restrict__ cb,
    const float* __restrict__ gate, const float* __restrict__ wl,
    float* __restrict__ out, float* __restrict__ pout, int vb, int tid)
{
    constexpr int H = 28, W = 28;
    constexpr int CIN = CIN1 + CIN2;
    constexpr int CG  = 2;
    constexpr int NCG = COUT / CG;
    constexpr int TOTAL = BATCH * 14 * 7;

    const unsigned bid = (unsigned)vb;
    const unsigned xcd = bid & 7u;
    const unsigned sub = bid >> 3;
    const unsigned cgq = sub % NCG;
    const unsigned tl  = sub / NCG;
    const unsigned tile = tl * 8u + xcd;
    const int c0 = (int)cgq * CG;

    __syncthreads();                 // protect wlds reuse across vb iterations
    for (int idx = tid; idx < CIN * 72; idx += 256) {
        const int ci = idx / 72;
        const int r  = idx % 72;
        const int k  = r / 8;
        const int je = r % 8;
        wlds[idx] = cw[((size_t)((je & 3) * COUT + c0 + (je >> 2)) * CIN + ci) * 9 + k];
    }
    __syncthreads();

    const int t = (int)tile * 256 + tid;
    if (t >= TOTAL) return;          // TOTAL%256==0: never taken (no sync below)
    const int b  = t / 98;
    const int r  = t - b * 98;
    const int hh = r / 7;
    const int q  = r - hh * 7;
    const int h0 = 2 * hh;
    const int w0 = 4 * q;

    const float4 gv4 = ld4(gate + b * 4);
    const float gt0 = gv4.x, gt1 = gv4.y, gt2 = gv4.z, gt3 = gv4.w;

    const float rt = (h0 > 0)     ? 1.0f : 0.0f;
    const float rb = (h0 + 2 < H) ? 1.0f : 0.0f;
    const float cl = (w0 > 0)     ? 1.0f : 0.0f;
    const float cr = (w0 + 4 < W) ? 1.0f : 0.0f;

    float acc[2][4][CG][4];
    #pragma unroll
    for (int j = 0; j < CG; ++j) {
        #pragma unroll
        for (int e = 0; e < 4; ++e) {
            const float bv = cb[e * COUT + c0 + j];
            #pragma unroll
            for (int rr = 0; rr < 2; ++rr)
                #pragma unroll
                for (int p = 0; p < 4; ++p) acc[rr][p][j][e] = bv;
        }
    }

    const int rbase = (h0 - 1) * W + w0;
    const float* xb1 = x1 + (size_t)b * CIN1 * (H * W);
    const float* xb2 = (CIN2 > 0) ? (x2 + (size_t)b * CIN2 * (H * W)) : nullptr;

    auto xplane = [&](int ci) -> const float* {
        if constexpr (CIN2 > 0)
            return (ci < CIN1) ? (xb1 + ci * (H * W)) : (xb2 + (ci - CIN1) * (H * W));
        else
            return xb1 + ci * (H * W);
    };
    auto load_taps = [&](int ci, float v[4][6]) {
        const float* rp = xplane(ci) + rbase;
        #pragma unroll
        for (int rr = 0; rr < 4; ++rr) {
            const float4 c = ld4(rp + rr * W);
            v[rr][0] = rp[rr * W - 1];
            v[rr][1] = c.x; v[rr][2] = c.y; v[rr][3] = c.z; v[rr][4] = c.w;
            v[rr][5] = rp[rr * W + 4];
        }
    };
    auto fma_taps = [&](int ci, const float v[4][6]) {
        float mv[4][6];
        #pragma unroll
        for (int rr = 0; rr < 4; ++rr) {
            #pragma unroll
            for (int c = 0; c < 6; ++c) mv[rr][c] = v[rr][c];
            mv[rr][0] *= cl;
            mv[rr][5] *= cr;
        }
        #pragma unroll
        for (int c = 0; c < 6; ++c) { mv[0][c] *= rt; mv[3][c] *= rb; }
        const float4* wp = (const float4*)&wlds[ci * 72];
        #pragma unroll
        for (int k = 0; k < 9; ++k) {
            const float4 wA = wp[k * 2];
            const float4 wB = wp[k * 2 + 1];
            const int kh = k / 3, kw = k % 3;
            #pragma unroll
            for (int rr = 0; rr < 2; ++rr) {
                #pragma unroll
                for (int p = 0; p < 4; ++p) {
                    const float tap = mv[rr + kh][p + kw];
                    acc[rr][p][0][0] = fmaf(tap, wA.x, acc[rr][p][0][0]);
                    acc[rr][p][0][1] = fmaf(tap, wA.y, acc[rr][p][0][1]);
                    acc[rr][p][0][2] = fmaf(tap, wA.z, acc[rr][p][0][2]);
                    acc[rr][p][0][3] = fmaf(tap, wA.w, acc[rr][p][0][3]);
                    acc[rr][p][1][0] = fmaf(tap, wB.x, acc[rr][p][1][0]);
                    acc[rr][p][1][1] = fmaf(tap, wB.y, acc[rr][p][1][1]);
                    acc[rr][p][1][2] = fmaf(tap, wB.z, acc[rr][p][1][2]);
                    acc[rr][p][1][3] = fmaf(tap, wB.w, acc[rr][p][1][3]);
                }
            }
        }
    };

    float vA[4][6], vB[4][6];
    load_taps(0, vA);
    #pragma unroll 1
    for (int ci = 0; ci + 2 <= CIN; ci += 2) {
        load_taps(ci + 1, vB);
        fma_taps(ci, vA);
        if (ci + 2 < CIN) load_taps(ci + 2, vA);
        fma_taps(ci + 1, vB);
    }
    if constexpr (CIN & 1) {
        fma_taps(CIN - 1, vA);
    }

    float s[2][4][CG];
    #pragma unroll
    for (int rr = 0; rr < 2; ++rr)
        #pragma unroll
        for (int p = 0; p < 4; ++p)
            #pragma unroll
            for (int j = 0; j < CG; ++j)
                s[rr][p][j] = gt0 * fmaxf(acc[rr][p][j][0], 0.f)
                            + gt1 * fmaxf(acc[rr][p][j][1], 0.f)
                            + gt2 * fmaxf(acc[rr][p][j][2], 0.f)
                            + gt3 * fmaxf(acc[rr][p][j][3], 0.f);

    if constexpr (PARTIAL) {
        const float w0f = wl[c0], w1f = wl[c0 + 1];
        float* op = out + ((size_t)cgq * BATCH + b) * (H * W) + h0 * W + w0;
        #pragma unroll
        for (int rr = 0; rr < 2; ++rr) {
            float4 o = {s[rr][0][0]*w0f + s[rr][0][1]*w1f,
                        s[rr][1][0]*w0f + s[rr][1][1]*w1f,
                        s[rr][2][0]*w0f + s[rr][2][1]*w1f,
                        s[rr][3][0]*w0f + s[rr][3][1]*w1f};
            *(float4*)(op + rr * W) = o;
        }
    } else {
        #pragma unroll
        for (int j = 0; j < CG; ++j) {
            float* op = out + ((size_t)b * COUT + c0 + j) * (H * W) + h0 * W + w0;
            #pragma unroll
            for (int rr = 0; rr < 2; ++rr) {
                float4 o = {s[rr][0][j], s[rr][1][j], s[rr][2][j], s[rr][3][j]};
                *(float4*)(op + rr * W) = o;
            }
        }
    }

    if constexpr (POOL) {
        constexpr int H2 = 14, W2 = 14;
        #pragma unroll
        for (int j = 0; j < CG; ++j) {
            float2 o;
            o.x = fmaxf(fmaxf(s[0][0][j], s[0][1][j]), fmaxf(s[1][0][j], s[1][1][j]));
            o.y = fmaxf(fmaxf(s[0][2][j], s[0][3][j]), fmaxf(s[1][2][j], s[1][3][j]));
            float* pp = pout + ((size_t)b * COUT + c0 + j) * (H2 * W2)
                        + hh * W2 + (w0 >> 1);
            *(float2*)pp = o;
        }
    }
}

// ---------------- generic 4-row strip conv (14x14 / 7x7) --------------------
template <int CIN1, int CIN2, int COUT, int H, int W, int POOL>
__device__ __forceinline__ void dev_conv4(
    const float* __restrict__ x1, const float* __restrict__ x2,
    const float* __restrict__ cw, const float* __restrict__ cb,
    const float* __restrict__ gate,
    float* __restrict__ out, float* __restrict__ pout, int vb, int tid)
{
    constexpr int CIN = CIN1 + CIN2;
    constexpr int CG  = 2;
    constexpr int NCG = COUT / CG;
    constexpr int HG  = (H + 3) / 4;
    constexpr int TOTAL = BATCH * HG * W;

    const unsigned bid = (unsigned)vb;
    const unsigned xcd = bid & 7u;
    const unsigned sub = bid >> 3;
    const unsigned cgq = sub % NCG;
    const unsigned tl  = sub / NCG;
    const unsigned tile = tl * 8u + xcd;
    const int c0 = (int)cgq * CG;

    __syncthreads();
    for (int idx = tid; idx < CIN * 72; idx += 256) {
        const int ci = idx / 72;
        const int r  = idx % 72;
        const int k  = r / 8;
        const int je = r % 8;
        wlds[idx] = cw[((size_t)((je & 3) * COUT + c0 + (je >> 2)) * CIN + ci) * 9 + k];
    }
    __syncthreads();

    const int t = (int)tile * 256 + tid;
    if (t >= TOTAL) return;
    const int b  = t / (HG * W);
    const int r  = t - b * (HG * W);
    const int hg = r / W;
    const int w  = r - hg * W;
    const int h0 = hg * 4;

    const float4 gv4 = ld4(gate + b * 4);
    const float gt0 = gv4.x, gt1 = gv4.y, gt2 = gv4.z, gt3 = gv4.w;

    float m[6][3];
    #pragma unroll
    for (int rr = 0; rr < 6; ++rr) {
        const int y = h0 - 1 + rr;
        const float my = (y >= 0 && y < H) ? 1.0f : 0.0f;
        #pragma unroll
        for (int dc = 0; dc < 3; ++dc) {
            const int xx = w - 1 + dc;
            m[rr][dc] = ((xx >= 0 && xx < W) ? 1.0f : 0.0f) * my;
        }
    }
    const int base = (h0 - 1) * W + (w - 1);

    float acc[4][CG][4];
    #pragma unroll
    for (int j = 0; j < CG; ++j) {
        #pragma unroll
        for (int e = 0; e < 4; ++e) {
            const float bv = cb[e * COUT + c0 + j];
            #pragma unroll
            for (int rr = 0; rr < 4; ++rr) acc[rr][j][e] = bv;
        }
    }

    const float* xb1 = x1 + (size_t)b * CIN1 * (H * W);
    const float* xb2 = (CIN2 > 0) ? (x2 + (size_t)b * CIN2 * (H * W)) : nullptr;

    auto xplane = [&](int ci) -> const float* {
        if constexpr (CIN2 > 0)
            return (ci < CIN1) ? (xb1 + ci * (H * W)) : (xb2 + (ci - CIN1) * (H * W));
        else
            return xb1 + ci * (H * W);
    };
    auto load_taps = [&](int ci, float v[6][3]) {
        const float* xp = xplane(ci);
        #pragma unroll
        for (int rr = 0; rr < 6; ++rr)
            #pragma unroll
            for (int dc = 0; dc < 3; ++dc)
                v[rr][dc] = xp[base + rr * W + dc] * m[rr][dc];
    };
    auto fma_taps = [&](int ci, const float v[6][3]) {
        const float4* wp = (const float4*)&wlds[ci * 72];
        #pragma unroll
        for (int k = 0; k < 9; ++k) {
            const float4 wA = wp[k * 2];
            const float4 wB = wp[k * 2 + 1];
            const int kh = k / 3, kw = k % 3;
            #pragma unroll
            for (int rr = 0; rr < 4; ++rr) {
                const float tap = v[rr + kh][kw];
                acc[rr][0][0] = fmaf(tap, wA.x, acc[rr][0][0]);
                acc[rr][0][1] = fmaf(tap, wA.y, acc[rr][0][1]);
                acc[rr][0][2] = fmaf(tap, wA.z, acc[rr][0][2]);
                acc[rr][0][3] = fmaf(tap, wA.w, acc[rr][0][3]);
                acc[rr][1][0] = fmaf(tap, wB.x, acc[rr][1][0]);
                acc[rr][1][1] = fmaf(tap, wB.y, acc[rr][1][1]);
                acc[rr][1][2] = fmaf(tap, wB.z, acc[rr][1][2]);
                acc[rr][1][3] = fmaf(tap, wB.w, acc[rr][1][3]);
            }
        }
    };

    float vA[6][3], vB[6][3];
    load_taps(0, vA);
    #pragma unroll 1
    for (int ci = 0; ci + 2 <= CIN; ci += 2) {
        load_taps(ci + 1, vB);
        fma_taps(ci, vA);
        if (ci + 2 < CIN) load_taps(ci + 2, vA);
        fma_taps(ci + 1, vB);
    }
    if constexpr (CIN & 1) {
        fma_taps(CIN - 1, vA);
    }

    float s[4][CG];
    #pragma unroll
    for (int rr = 0; rr < 4; ++rr)
        #pragma unroll
        for (int j = 0; j < CG; ++j)
            s[rr][j] = gt0 * fmaxf(acc[rr][j][0], 0.f)
                     + gt1 * fmaxf(acc[rr][j][1], 0.f)
                     + gt2 * fmaxf(acc[rr][j][2], 0.f)
                     + gt3 * fmaxf(acc[rr][j][3], 0.f);

    #pragma unroll
    for (int j = 0; j < CG; ++j) {
        float* op = out + ((size_t)b * COUT + c0 + j) * (H * W) + h0 * W + w;
        #pragma unroll
        for (int rr = 0; rr < 4; ++rr)
            if (h0 + rr < H) op[rr * W] = s[rr][j];
    }

    if constexpr (POOL) {
        constexpr int H2 = H / 2, W2 = W / 2;
        #pragma unroll
        for (int j = 0; j < CG; ++j) {
            float cm0 = fmaxf(s[0][j], s[1][j]);
            float cm1 = fmaxf(s[2][j], s[3][j]);
            const float o0 = fmaxf(cm0, __shfl_xor(cm0, 1, 64));
            const float o1 = fmaxf(cm1, __shfl_xor(cm1, 1, 64));
            if ((w & 1) == 0) {
                const int pr0 = h0 >> 1;
                float* pp = pout + ((size_t)b * COUT + c0 + j) * (H2 * W2) + (w >> 1);
                if (pr0     < H2) pp[pr0 * W2]       = o0;
                if (pr0 + 1 < H2) pp[(pr0 + 1) * W2] = o1;
            }
        }
    }
}

// ---------------- bilinear x2 upsample (grid-strided) ----------------------
template <int N>
__device__ __forceinline__ void dev_up2(
    const float* __restrict__ in, float* __restrict__ out, int BC,
    int gid, int stride)
{
    constexpr int M = 2 * N;
    const int total = BC * M * M;
    const float scale = (float)((double)(N - 1) / (double)(M - 1));
    for (int idx = gid; idx < total; idx += stride) {
        const int x = idx % M;
        int tmp = idx / M;
        const int y = tmp % M;
        const int bc = tmp / M;
        const float cy = (float)y * scale;
        const float cx = (float)x * scale;
        const int iy0 = (int)floorf(cy);
        const int ix0 = (int)floorf(cx);
        const int iy1 = min(iy0 + 1, N - 1);
        const int ix1 = min(ix0 + 1, N - 1);
        const float wy = cy - (float)iy0;
        const float wx = cx - (float)ix0;
        const float* p = in + (size_t)bc * N * N;
        const float v00 = p[iy0 * N + ix0], v01 = p[iy0 * N + ix1];
        const float v10 = p[iy1 * N + ix0], v11 = p[iy1 * N + ix1];
        const float a0 = v00 * (1.0f - wy) + v10 * wy;
        const float a1 = v01 * (1.0f - wy) + v11 * wy;
        out[idx] = a0 * (1.0f - wx) + a1 * wx;
    }
}

// ---------------- the cooperative mega-kernel ------------------------------
__global__ void __launch_bounds__(256) meganet(Params P) {
    cg::grid_group grid = cg::this_grid();
    const int tid = threadIdx.x;
    const int nb  = (int)gridDim.x;
    const int gid = (int)blockIdx.x * 256 + tid;
    const int gstride = nb * 256;

    float* graw[5]; float* gate[5];
    #pragma unroll
    for (int l = 0; l < 5; ++l) {
        graw[l] = P.graw + (size_t)l * BATCH * 4;
        gate[l] = P.gate + (size_t)l * BATCH * 4;
    }

    // P0: xpad <- x
    for (int i = gid; i < BATCH * 784; i += gstride) P.xpad[i] = P.x[i];
    grid.sync();

    // ---- layer 1
    for (int vb = blockIdx.x; vb < 1024; vb += nb)
        dev_gate_v4<784, 0>(P.x, nullptr, P.gw[0], P.gb[0], P.nw[0], P.nb[0],
                            P.eps[0], graw[0], vb, tid);
    grid.sync();
    dev_finalize(graw[0], P.kp, gate[0], tid, nb);
    grid.sync();
    for (int vb = blockIdx.x; vb < 3920; vb += nb)
        dev_conv_q4<1, 0, 10, 1, 0>(P.xpad, nullptr, P.cw[0], P.cb[0],
                                    gate[0], nullptr, P.conv1, P.p1, vb, tid);
    grid.sync();

    // ---- layer 2
    for (int vb = blockIdx.x; vb < 1024; vb += nb)
        dev_gate_v4<1960, 0>(P.p1, nullptr, P.gw[1], P.gb[1], P.nw[1], P.nb[1],
                             P.eps[1], graw[1], vb, tid);
    grid.sync();
    dev_finalize(graw[1], P.kp, gate[1], tid, nb);
    grid.sync();
    for (int vb = blockIdx.x; vb < 2240; vb += nb)
        dev_conv4<10, 0, 10, 14, 14, 1>(P.p1, nullptr, P.cw[1], P.cb[1],
                                        gate[1], P.conv2, P.p2, vb, tid);
    grid.sync();

    // ---- layer 3
    for (int vb = blockIdx.x; vb < 2048; vb += nb)
        dev_gate_s<490>(P.p2, P.gw[2], P.gb[2], P.nw[2], P.nb[2],
                        P.eps[2], graw[2], vb, tid);
    grid.sync();
    dev_finalize(graw[2], P.kp, gate[2], tid, nb);
    grid.sync();
    for (int vb = blockIdx.x; vb < 1120; vb += nb)
        dev_conv4<10, 0, 20, 7, 7, 0>(P.p2, nullptr, P.cw[2], P.cb[2],
                                      gate[2], P.conv3, nullptr, vb, tid);
    grid.sync();
    dev_up2<7>(P.conv3, P.up3, BATCH * 20, gid, gstride);
    grid.sync();

    // ---- layer 4
    for (int vb = blockIdx.x; vb < 1024; vb += nb)
        dev_gate_v4<3920, 1960>(P.up3, P.conv2, P.gw[3], P.gb[3], P.nw[3], P.nb[3],
                                P.eps[3], graw[3], vb, tid);
    grid.sync();
    dev_finalize(graw[3], P.kp, gate[3], tid, nb);
    grid.sync();
    for (int vb = blockIdx.x; vb < 2240; vb += nb)
        dev_conv4<20, 10, 10, 14, 14, 0>(P.up3, P.conv2, P.cw[3], P.cb[3],
                                         gate[3], P.m4, nullptr, vb, tid);
    grid.sync();
    dev_up2<14>(P.m4, P.up4, BATCH * 10, gid, gstride);
    grid.sync();

    // ---- layer 5
    for (int vb = blockIdx.x; vb < 1024; vb += nb)
        dev_gate_v4<7840, 7840>(P.up4, P.conv1, P.gw[4], P.gb[4], P.nw[4], P.nb[4],
                                P.eps[4], graw[4], vb, tid);
    grid.sync();
    dev_finalize(graw[4], P.kp, gate[4], tid, nb);
    grid.sync();
    for (int vb = blockIdx.x; vb < 3920; vb += nb)
        dev_conv_q4<10, 10, 10, 0, 1>(P.up4, P.conv1, P.cw[4], P.cb[4],
                                      gate[4], P.wlast, P.m5p, nullptr, vb, tid);
    grid.sync();

    // P18: out = bias + sum of 5 partial slices (float4 units)
    {
        const float bias = P.blast[0];
        const int total4 = BATCH * 196;
        for (int i = gid; i < total4; i += gstride) {
            const int b = i / 196;
            const int s4 = i % 196;
            float4 acc = {bias, bias, bias, bias};
            #pragma unroll
            for (int cgq = 0; cgq < 5; ++cgq) {
                const float4 v = ld4(P.m5p + ((size_t)cgq * BATCH + b) * 784 + s4 * 4);
                acc.x += v.x; acc.y += v.y; acc.z += v.z; acc.w += v.w;
            }
            ((float4*)P.out)[i] = acc;
        }
    }
}

// ---------------------------------------------------------------------------
extern "C" void kernel_launch(void* const* d_in, const int* in_sizes, int n_in,
                              void* d_out, int out_size, void* d_ws, size_t ws_size,
                              hipStream_t stream)
{
    Params P;
    P.x = (const float*)d_in[0];
    for (int l = 0; l < 5; ++l) {
        P.cw[l]  = (const float*)d_in[1 + 7 * l + 0];
        P.cb[l]  = (const float*)d_in[1 + 7 * l + 1];
        P.gw[l]  = (const float*)d_in[1 + 7 * l + 2];
        P.gb[l]  = (const float*)d_in[1 + 7 * l + 3];
        P.nw[l]  = (const float*)d_in[1 + 7 * l + 4];
        P.nb[l]  = (const float*)d_in[1 + 7 * l + 5];
        P.eps[l] = (const float*)d_in[1 + 7 * l + 6];
    }
    P.wlast = (const float*)d_in[36];
    P.blast = (const float*)d_in[37];
    P.kp    = (const int*)d_in[38];
    P.out   = (float*)d_out;

    float* ws = (float*)d_ws;
    P.conv1 = ws + O_CONV1;
    P.xpad  = ws + O_XPAD;
    P.p1    = ws + O_P1;
    P.conv2 = ws + O_CONV2;
    P.p2    = ws + O_P2;
    P.conv3 = ws + O_CONV3;
    P.up3   = ws + O_UP3;
    P.m4    = ws + O_M4;
    P.up4   = ws + O_UP4;
    P.m5p   = ws + O_M5P;
    P.graw  = ws + O_GRAW;
    P.gate  = ws + O_GATE;

    // grid = co-resident capacity (query each call; deterministic). Phases are
    // virtual-block-strided, so ANY grid size is correct — no deadlock risk.
    int maxB = 0;
    hipOccupancyMaxActiveBlocksPerMultiprocessor(
        &maxB, reinterpret_cast<const void*>(&meganet), 256, 0);
    if (maxB < 1) maxB = 1;
    int grid = maxB * 256;           // 256 CUs on MI355X
    if (grid > 1024) grid = 1024;    // >=1 wave of virtual blocks per phase

    void* args[] = {(void*)&P};
    hipLaunchCooperativeKernel(reinterpret_cast<const void*>(&meganet),
                               dim3(grid), dim3(256), args, 0, stream);
}

// Round 14
// 971.362 us; speedup vs baseline: 1.5760x; 1.5760x over previous
//
#include <hip/hip_runtime.h>
#include <hip/hip_bf16.h>
#include <math.h>

// ---------------------------------------------------------------------------
// Generalised gated MoE U-net, B=2048, E=4, W=10, fp32 throughout.
// Round 14: R12 structure + LAST-BLOCK gate finalize (threadfence + counter;
//   final block does colsum/top-k/softmax -> gate[] table). Removes 5
//   gate_reduce dispatches and per-conv-thread topk/softmax (convs ld4 gate).
//   R13's cooperative mega-kernel regressed 2x: grid.sync() ~45us each on
//   8-XCD MI355X — never again.
// ---------------------------------------------------------------------------

constexpr int BATCH = 2048;

// ---------------- workspace layout (floats) ----------------
constexpr size_t PADF    = 1024;
constexpr size_t F_CONV1 = (size_t)BATCH * 10 * 784;
constexpr size_t F_XPAD  = (size_t)BATCH * 784;
constexpr size_t F_P1    = (size_t)BATCH * 10 * 196;
constexpr size_t F_CONV2 = F_P1;
constexpr size_t F_P2    = (size_t)BATCH * 10 * 49;
constexpr size_t F_CONV3 = (size_t)BATCH * 20 * 49;
constexpr size_t F_UP3   = (size_t)BATCH * 20 * 196;
constexpr size_t F_M4    = F_P1;
constexpr size_t F_UP4   = F_CONV1;
constexpr size_t F_M5    = F_CONV1;

constexpr size_t O_CONV1 = PADF;
constexpr size_t O_Z2    = O_CONV1 + F_CONV1 + PADF;
constexpr size_t O_XPAD  = O_Z2;
constexpr size_t O_P1    = O_XPAD + F_XPAD + PADF;
constexpr size_t O_CONV2 = O_P1 + F_P1 + PADF;
constexpr size_t O_P2    = O_CONV2 + F_CONV2 + PADF;
constexpr size_t O_CONV3 = O_P2 + F_P2 + PADF;
constexpr size_t O_UP3   = O_CONV3 + F_CONV3 + PADF;
constexpr size_t O_M4    = O_UP3 + F_UP3 + PADF;
constexpr size_t O_UP4   = O_Z2;                        // overlays dead xpad..up3
constexpr size_t O_M5    = O_Z2 + F_UP4 + PADF;         // overlays dead m4 zone
constexpr size_t O_GRAW  = O_M5 + F_M5 + PADF;
constexpr size_t O_GATE  = O_GRAW + 5 * (size_t)BATCH * 4 + PADF;
constexpr size_t O_CTR   = O_GATE + 5 * (size_t)BATCH * 4 + PADF;  // 5 uint

__device__ __forceinline__ float softplusf(float z) {
    return fmaxf(z, 0.0f) + log1pf(expf(-fabsf(z)));
}
__device__ __forceinline__ float4 ld4(const float* p) { return *(const float4*)p; }

constexpr int cdivc(int a, int b) { return (a + b - 1) / b; }
constexpr int pb4(int H, int W) {
    return cdivc(BATCH * ((H + 3) / 4) * W, 256);
}

// ---------------- last-block finalize: colsum + top-k + masked softmax -----
__device__ __forceinline__ void finalize_in_last_block(
    const float* __restrict__ graw, const int* __restrict__ kp,
    float* __restrict__ gate, int tid)
{
    __shared__ float fred[4][4];
    float a0 = 0.f, a1 = 0.f, a2 = 0.f, a3 = 0.f;
    for (int b = tid; b < BATCH; b += 256) {
        const float4 v = ld4(graw + b * 4);
        a0 += v.x; a1 += v.y; a2 += v.z; a3 += v.w;
    }
    #pragma unroll
    for (int m = 32; m >= 1; m >>= 1) {
        a0 += __shfl_xor(a0, m, 64); a1 += __shfl_xor(a1, m, 64);
        a2 += __shfl_xor(a2, m, 64); a3 += __shfl_xor(a3, m, 64);
    }
    const int wave = tid >> 6, lane = tid & 63;
    if (lane == 0) {
        fred[wave][0] = a0; fred[wave][1] = a1;
        fred[wave][2] = a2; fred[wave][3] = a3;
    }
    __syncthreads();
    float cs[4];
    #pragma unroll
    for (int e = 0; e < 4; ++e)
        cs[e] = fred[0][e] + fred[1][e] + fred[2][e] + fred[3][e];

    int k = kp[0];
    k = (k < 1) ? 1 : (k > 4 ? 4 : k);
    bool sel[4] = {false, false, false, false};
    for (int it = 0; it < k; ++it) {
        int bi = 0; float bv = -INFINITY;
        #pragma unroll
        for (int e = 0; e < 4; ++e)
            if (!sel[e] && cs[e] > bv) { bv = cs[e]; bi = e; }
        sel[bi] = true;
    }
    for (int b = tid; b < BATCH; b += 256) {
        float g[4];
        #pragma unroll
        for (int e = 0; e < 4; ++e) {
            const float v = graw[b * 4 + e];
            g[e] = sel[e] ? v : 0.0f;       // zero BEFORE softmax (reference)
        }
        const float mx = fmaxf(fmaxf(g[0], g[1]), fmaxf(g[2], g[3]));
        const float e0 = expf(g[0]-mx), e1 = expf(g[1]-mx);
        const float e2 = expf(g[2]-mx), e3 = expf(g[3]-mx);
        const float inv = 1.0f / (e0 + e1 + e2 + e3);
        float4 o = {e0*inv, e1*inv, e2*inv, e3*inv};
        *(float4*)(gate + b * 4) = o;
    }
}

// ---------------- gate: block per 2 samples + last-block finalize ----------
template <int C1HW, int C2HW>
__global__ __launch_bounds__(256) void gate_block_v4(
    const float* __restrict__ x1, const float* __restrict__ x2,
    const float* __restrict__ gw, const float* __restrict__ gb,
    const float* __restrict__ nw, const float* __restrict__ nb,
    const float* __restrict__ eps, const int* __restrict__ kp,
    float* __restrict__ graw, float* __restrict__ gate,
    unsigned* __restrict__ ctr)
{
    constexpr int DV = (C1HW + C2HW) / 4;
    const int b0  = blockIdx.x * 2;
    const int tid = threadIdx.x;

    float ga[2][4] = {}, na[2][4] = {};

    for (int g = tid; g < DV; g += 256) {
        const int d = g * 4;
        float4 xv[2];
        #pragma unroll
        for (int ss = 0; ss < 2; ++ss) {
            const int b = b0 + ss;
            if constexpr (C2HW > 0) {
                xv[ss] = (d < C1HW) ? ld4(x1 + (size_t)b * C1HW + d)
                                    : ld4(x2 + (size_t)b * C2HW + (d - C1HW));
            } else {
                xv[ss] = ld4(x1 + (size_t)b * C1HW + d);
            }
        }
        #pragma unroll
        for (int j = 0; j < 4; ++j) {
            const float4 gv = ((const float4*)gw)[d + j];
            const float4 nv = ((const float4*)nw)[d + j];
            #pragma unroll
            for (int ss = 0; ss < 2; ++ss) {
                const float val = (&xv[ss].x)[j];
                ga[ss][0] = fmaf(val, gv.x, ga[ss][0]);
                ga[ss][1] = fmaf(val, gv.y, ga[ss][1]);
                ga[ss][2] = fmaf(val, gv.z, ga[ss][2]);
                ga[ss][3] = fmaf(val, gv.w, ga[ss][3]);
                na[ss][0] = fmaf(val, nv.x, na[ss][0]);
                na[ss][1] = fmaf(val, nv.y, na[ss][1]);
                na[ss][2] = fmaf(val, nv.z, na[ss][2]);
                na[ss][3] = fmaf(val, nv.w, na[ss][3]);
            }
        }
    }
    #pragma unroll
    for (int m = 32; m >= 1; m >>= 1) {
        #pragma unroll
        for (int ss = 0; ss < 2; ++ss)
            #pragma unroll
            for (int e = 0; e < 4; ++e) {
                ga[ss][e] += __shfl_xor(ga[ss][e], m, 64);
                na[ss][e] += __shfl_xor(na[ss][e], m, 64);
            }
    }
    __shared__ float red[4][16];
    __shared__ int amLast;
    const int wave = tid >> 6, lane = tid & 63;
    if (lane == 0) {
        #pragma unroll
        for (int ss = 0; ss < 2; ++ss)
            #pragma unroll
            for (int e = 0; e < 4; ++e) {
                red[wave][ss * 8 + e]     = ga[ss][e];
                red[wave][ss * 8 + 4 + e] = na[ss][e];
            }
    }
    __syncthreads();
    if (tid < 2) {
        const int ss = tid;
        #pragma unroll
        for (int e = 0; e < 4; ++e) {
            const float G = red[0][ss*8+e] + red[1][ss*8+e]
                          + red[2][ss*8+e] + red[3][ss*8+e];
            const float N = red[0][ss*8+4+e] + red[1][ss*8+4+e]
                          + red[2][ss*8+4+e] + red[3][ss*8+4+e];
            graw[(b0 + ss) * 4 + e] = G + gb[e] + eps[e] * softplusf(N + nb[e]);
        }
    }
    __syncthreads();
    if (tid == 0) {
        __threadfence();                          // release graw writes
        const unsigned prev = atomicAdd(ctr, 1u);
        amLast = (prev == gridDim.x - 1) ? 1 : 0;
    }
    __syncthreads();
    if (amLast) {
        __threadfence();                          // acquire others' graw
        finalize_in_last_block(graw, kp, gate, tid);
    }
}

// scalar variant (D=490), 1 sample per block + last-block finalize
template <int D>
__global__ __launch_bounds__(256) void gate_block_s(
    const float* __restrict__ x1,
    const float* __restrict__ gw, const float* __restrict__ gb,
    const float* __restrict__ nw, const float* __restrict__ nb,
    const float* __restrict__ eps, const int* __restrict__ kp,
    float* __restrict__ graw, float* __restrict__ gate,
    unsigned* __restrict__ ctr)
{
    const int b   = blockIdx.x;
    const int tid = threadIdx.x;

    float ga0=0,ga1=0,ga2=0,ga3=0,na0=0,na1=0,na2=0,na3=0;
    for (int d = tid; d < D; d += 256) {
        const float val = x1[(size_t)b * D + d];
        const float4 gv = ((const float4*)gw)[d];
        const float4 nv = ((const float4*)nw)[d];
        ga0 = fmaf(val, gv.x, ga0); ga1 = fmaf(val, gv.y, ga1);
        ga2 = fmaf(val, gv.z, ga2); ga3 = fmaf(val, gv.w, ga3);
        na0 = fmaf(val, nv.x, na0); na1 = fmaf(val, nv.y, na1);
        na2 = fmaf(val, nv.z, na2); na3 = fmaf(val, nv.w, na3);
    }
    #pragma unroll
    for (int m = 32; m >= 1; m >>= 1) {
        ga0 += __shfl_xor(ga0, m, 64); ga1 += __shfl_xor(ga1, m, 64);
        ga2 += __shfl_xor(ga2, m, 64); ga3 += __shfl_xor(ga3, m, 64);
        na0 += __shfl_xor(na0, m, 64); na1 += __shfl_xor(na1, m, 64);
        na2 += __shfl_xor(na2, m, 64); na3 += __shfl_xor(na3, m, 64);
    }
    __shared__ float red[4][8];
    __shared__ int amLast;
    const int wave = tid >> 6, lane = tid & 63;
    if (lane == 0) {
        red[wave][0] = ga0; red[wave][1] = ga1; red[wave][2] = ga2; red[wave][3] = ga3;
        red[wave][4] = na0; red[wave][5] = na1; red[wave][6] = na2; red[wave][7] = na3;
    }
    __syncthreads();
    if (tid == 0) {
        #pragma unroll
        for (int e = 0; e < 4; ++e) {
            const float G = red[0][e]+red[1][e]+red[2][e]+red[3][e];
            const float N = red[0][4+e]+red[1][4+e]+red[2][4+e]+red[3][4+e];
            graw[b * 4 + e] = G + gb[e] + eps[e] * softplusf(N + nb[e]);
        }
        __threadfence();
        const unsigned prev = atomicAdd(ctr, 1u);
        amLast = (prev == gridDim.x - 1) ? 1 : 0;
    }
    __syncthreads();
    if (amLast) {
        __threadfence();
        finalize_in_last_block(graw, kp, gate, tid);
    }
}

// ---------------- quad-pixel conv (2-row x 4-col; H=W=28 layers) -----------
template <int CIN1, int CIN2, int COUT, int POOL>
__global__ __launch_bounds__(256) void moe_conv_q4(
    const float* __restrict__ x1, const float* __restrict__ x2,
    const float* __restrict__ cw, const float* __restrict__ cb,
    const float* __restrict__ gate,
    float* __restrict__ out, float* __restrict__ pout)
{
    constexpr int H = 28, W = 28;
    constexpr int CIN = CIN1 + CIN2;
    constexpr int CG  = 2;
    constexpr int NCG = COUT / CG;
    constexpr int TOTAL = BATCH * 14 * 7;

    __shared__ __align__(16) float wlds[CIN * 72];

    const unsigned bid = blockIdx.x;
    const unsigned xcd = bid & 7u;
    const unsigned sub = bid >> 3;
    const unsigned cg  = sub % NCG;
    const unsigned tl  = sub / NCG;
    const unsigned tile = tl * 8u + xcd;
    const int c0 = (int)cg * CG;

    for (int idx = threadIdx.x; idx < CIN * 72; idx += 256) {
        const int ci = idx / 72;
        const int r  = idx % 72;
        const int k  = r / 8;
        const int je = r % 8;
        wlds[idx] = cw[((size_t)((je & 3) * COUT + c0 + (je >> 2)) * CIN + ci) * 9 + k];
    }
    __syncthreads();

    const int t = (int)tile * 256 + (int)threadIdx.x;
    if (t >= TOTAL) return;
    const int b  = t / 98;
    const int r  = t - b * 98;
    const int hh = r / 7;
    const int q  = r - hh * 7;
    const int h0 = 2 * hh;
    const int w0 = 4 * q;

    const float4 gv4 = ld4(gate + b * 4);

    const float rt = (h0 > 0)     ? 1.0f : 0.0f;
    const float rb = (h0 + 2 < H) ? 1.0f : 0.0f;
    const float cl = (w0 > 0)     ? 1.0f : 0.0f;
    const float cr = (w0 + 4 < W) ? 1.0f : 0.0f;

    float acc[2][4][CG][4];
    #pragma unroll
    for (int j = 0; j < CG; ++j) {
        #pragma unroll
        for (int e = 0; e < 4; ++e) {
            const float bv = cb[e * COUT + c0 + j];
            #pragma unroll
            for (int rr = 0; rr < 2; ++rr)
                #pragma unroll
                for (int p = 0; p < 4; ++p) acc[rr][p][j][e] = bv;
        }
    }

    const int rbase = (h0 - 1) * W + w0;
    const float* xb1 = x1 + (size_t)b * CIN1 * (H * W);
    const float* xb2 = (CIN2 > 0) ? (x2 + (size_t)b * CIN2 * (H * W)) : nullptr;

    auto xplane = [&](int ci) -> const float* {
        if constexpr (CIN2 > 0)
            return (ci < CIN1) ? (xb1 + ci * (H * W)) : (xb2 + (ci - CIN1) * (H * W));
        else
            return xb1 + ci * (H * W);
    };
    auto load_taps = [&](int ci, float v[4][6]) {
        const float* rp = xplane(ci) + rbase;
        #pragma unroll
        for (int rr = 0; rr < 4; ++rr) {
            const float4 c = ld4(rp + rr * W);
            v[rr][0] = rp[rr * W - 1];
            v[rr][1] = c.x; v[rr][2] = c.y; v[rr][3] = c.z; v[rr][4] = c.w;
            v[rr][5] = rp[rr * W + 4];
        }
    };
    auto fma_taps = [&](int ci, const float v[4][6]) {
        float mv[4][6];
        #pragma unroll
        for (int rr = 0; rr < 4; ++rr) {
            #pragma unroll
            for (int c = 0; c < 6; ++c) mv[rr][c] = v[rr][c];
            mv[rr][0] *= cl;
            mv[rr][5] *= cr;
        }
        #pragma unroll
        for (int c = 0; c < 6; ++c) { mv[0][c] *= rt; mv[3][c] *= rb; }

        const float4* wp = (const float4*)&wlds[ci * 72];
        #pragma unroll
        for (int k = 0; k < 9; ++k) {
            const float4 wA = wp[k * 2];
            const float4 wB = wp[k * 2 + 1];
            const int kh = k / 3, kw = k % 3;
            #pragma unroll
            for (int rr = 0; rr < 2; ++rr) {
                #pragma unroll
                for (int p = 0; p < 4; ++p) {
                    const float tap = mv[rr + kh][p + kw];
                    acc[rr][p][0][0] = fmaf(tap, wA.x, acc[rr][p][0][0]);
                    acc[rr][p][0][1] = fmaf(tap, wA.y, acc[rr][p][0][1]);
                    acc[rr][p][0][2] = fmaf(tap, wA.z, acc[rr][p][0][2]);
                    acc[rr][p][0][3] = fmaf(tap, wA.w, acc[rr][p][0][3]);
                    acc[rr][p][1][0] = fmaf(tap, wB.x, acc[rr][p][1][0]);
                    acc[rr][p][1][1] = fmaf(tap, wB.y, acc[rr][p][1][1]);
                    acc[rr][p][1][2] = fmaf(tap, wB.z, acc[rr][p][1][2]);
                    acc[rr][p][1][3] = fmaf(tap, wB.w, acc[rr][p][1][3]);
                }
            }
        }
    };

    float vA[4][6], vB[4][6];
    load_taps(0, vA);
    #pragma unroll 1
    for (int ci = 0; ci + 2 <= CIN; ci += 2) {
        load_taps(ci + 1, vB);
        fma_taps(ci, vA);
        if (ci + 2 < CIN) load_taps(ci + 2, vA);
        fma_taps(ci + 1, vB);
    }
    if constexpr (CIN & 1) {
        fma_taps(CIN - 1, vA);
    }

    float s[2][4][CG];
    #pragma unroll
    for (int rr = 0; rr < 2; ++rr)
        #pragma unroll
        for (int p = 0; p < 4; ++p)
            #pragma unroll
            for (int j = 0; j < CG; ++j)
                s[rr][p][j] = gv4.x * fmaxf(acc[rr][p][j][0], 0.f)
                            + gv4.y * fmaxf(acc[rr][p][j][1], 0.f)
                            + gv4.z * fmaxf(acc[rr][p][j][2], 0.f)
                            + gv4.w * fmaxf(acc[rr][p][j][3], 0.f);

    #pragma unroll
    for (int j = 0; j < CG; ++j) {
        float* op = out + ((size_t)b * COUT + c0 + j) * (H * W) + h0 * W + w0;
        #pragma unroll
        for (int rr = 0; rr < 2; ++rr) {
            float4 o = {s[rr][0][j], s[rr][1][j], s[rr][2][j], s[rr][3][j]};
            *(float4*)(op + rr * W) = o;
        }
    }

    if constexpr (POOL) {
        constexpr int H2 = 14, W2 = 14;
        #pragma unroll
        for (int j = 0; j < CG; ++j) {
            float2 o;
            o.x = fmaxf(fmaxf(s[0][0][j], s[0][1][j]), fmaxf(s[1][0][j], s[1][1][j]));
            o.y = fmaxf(fmaxf(s[0][2][j], s[0][3][j]), fmaxf(s[1][2][j], s[1][3][j]));
            float* pp = pout + ((size_t)b * COUT + c0 + j) * (H2 * W2)
                        + hh * W2 + (w0 >> 1);
            *(float2*)pp = o;
        }
    }
}

// ---------------- generic 4-row strip conv (H=14 / H=7 layers) -------------
template <int CIN1, int CIN2, int COUT, int H, int W, int POOL>
__global__ __launch_bounds__(256) void moe_conv4(
    const float* __restrict__ x1, const float* __restrict__ x2,
    const float* __restrict__ cw, const float* __restrict__ cb,
    const float* __restrict__ gate,
    float* __restrict__ out, float* __restrict__ pout)
{
    constexpr int CIN = CIN1 + CIN2;
    constexpr int CG  = 2;
    constexpr int NCG = COUT / CG;
    constexpr int HG  = (H + 3) / 4;
    constexpr int TOTAL = BATCH * HG * W;

    __shared__ __align__(16) float wlds[CIN * 72];

    const unsigned bid = blockIdx.x;
    const unsigned xcd = bid & 7u;
    const unsigned sub = bid >> 3;
    const unsigned cg  = sub % NCG;
    const unsigned tl  = sub / NCG;
    const unsigned tile = tl * 8u + xcd;
    const int c0 = (int)cg * CG;

    for (int idx = threadIdx.x; idx < CIN * 72; idx += 256) {
        const int ci = idx / 72;
        const int r  = idx % 72;
        const int k  = r / 8;
        const int je = r % 8;
        wlds[idx] = cw[((size_t)((je & 3) * COUT + c0 + (je >> 2)) * CIN + ci) * 9 + k];
    }
    __syncthreads();

    const int t = (int)tile * 256 + (int)threadIdx.x;
    if (t >= TOTAL) return;
    const int b  = t / (HG * W);
    const int r  = t - b * (HG * W);
    const int hg = r / W;
    const int w  = r - hg * W;
    const int h0 = hg * 4;

    const float4 gv4 = ld4(gate + b * 4);

    float m[6][3];
    #pragma unroll
    for (int rr = 0; rr < 6; ++rr) {
        const int y = h0 - 1 + rr;
        const float my = (y >= 0 && y < H) ? 1.0f : 0.0f;
        #pragma unroll
        for (int dc = 0; dc < 3; ++dc) {
            const int xx = w - 1 + dc;
            m[rr][dc] = ((xx >= 0 && xx < W) ? 1.0f : 0.0f) * my;
        }
    }
    const int base = (h0 - 1) * W + (w - 1);

    float acc[4][CG][4];
    #pragma unroll
    for (int j = 0; j < CG; ++j) {
        #pragma unroll
        for (int e = 0; e < 4; ++e) {
            const float bv = cb[e * COUT + c0 + j];
            #pragma unroll
            for (int rr = 0; rr < 4; ++rr) acc[rr][j][e] = bv;
        }
    }

    const float* xb1 = x1 + (size_t)b * CIN1 * (H * W);
    const float* xb2 = (CIN2 > 0) ? (x2 + (size_t)b * CIN2 * (H * W)) : nullptr;

    auto xplane = [&](int ci) -> const float* {
        if constexpr (CIN2 > 0)
            return (ci < CIN1) ? (xb1 + ci * (H * W)) : (xb2 + (ci - CIN1) * (H * W));
        else
            return xb1 + ci * (H * W);
    };
    auto load_taps = [&](int ci, float v[6][3]) {
        const float* xp = xplane(ci);
        #pragma unroll
        for (int rr = 0; rr < 6; ++rr)
            #pragma unroll
            for (int dc = 0; dc < 3; ++dc)
                v[rr][dc] = xp[base + rr * W + dc] * m[rr][dc];
    };
    auto fma_taps = [&](int ci, const float v[6][3]) {
        const float4* wp = (const float4*)&wlds[ci * 72];
        #pragma unroll
        for (int k = 0; k < 9; ++k) {
            const float4 wA = wp[k * 2];
            const float4 wB = wp[k * 2 + 1];
            const int kh = k / 3, kw = k % 3;
            #pragma unroll
            for (int rr = 0; rr < 4; ++rr) {
                const float tap = v[rr + kh][kw];
                acc[rr][0][0] = fmaf(tap, wA.x, acc[rr][0][0]);
                acc[rr][0][1] = fmaf(tap, wA.y, acc[rr][0][1]);
                acc[rr][0][2] = fmaf(tap, wA.z, acc[rr][0][2]);
                acc[rr][0][3] = fmaf(tap, wA.w, acc[rr][0][3]);
                acc[rr][1][0] = fmaf(tap, wB.x, acc[rr][1][0]);
                acc[rr][1][1] = fmaf(tap, wB.y, acc[rr][1][1]);
                acc[rr][1][2] = fmaf(tap, wB.z, acc[rr][1][2]);
                acc[rr][1][3] = fmaf(tap, wB.w, acc[rr][1][3]);
            }
        }
    };

    float vA[6][3], vB[6][3];
    load_taps(0, vA);
    #pragma unroll 1
    for (int ci = 0; ci + 2 <= CIN; ci += 2) {
        load_taps(ci + 1, vB);
        fma_taps(ci, vA);
        if (ci + 2 < CIN) load_taps(ci + 2, vA);
        fma_taps(ci + 1, vB);
    }
    if constexpr (CIN & 1) {
        fma_taps(CIN - 1, vA);
    }

    float s[4][CG];
    #pragma unroll
    for (int rr = 0; rr < 4; ++rr)
        #pragma unroll
        for (int j = 0; j < CG; ++j)
            s[rr][j] = gv4.x * fmaxf(acc[rr][j][0], 0.f)
                     + gv4.y * fmaxf(acc[rr][j][1], 0.f)
                     + gv4.z * fmaxf(acc[rr][j][2], 0.f)
                     + gv4.w * fmaxf(acc[rr][j][3], 0.f);

    #pragma unroll
    for (int j = 0; j < CG; ++j) {
        float* op = out + ((size_t)b * COUT + c0 + j) * (H * W) + h0 * W + w;
        #pragma unroll
        for (int rr = 0; rr < 4; ++rr)
            if (h0 + rr < H) op[rr * W] = s[rr][j];
    }

    if constexpr (POOL) {
        constexpr int H2 = H / 2, W2 = W / 2;
        #pragma unroll
        for (int j = 0; j < CG; ++j) {
            float cm0 = fmaxf(s[0][j], s[1][j]);
            float cm1 = fmaxf(s[2][j], s[3][j]);
            const float o0 = fmaxf(cm0, __shfl_xor(cm0, 1, 64));
            const float o1 = fmaxf(cm1, __shfl_xor(cm1, 1, 64));
            if ((w & 1) == 0) {
                const int pr0 = h0 >> 1;
                float* pp = pout + ((size_t)b * COUT + c0 + j) * (H2 * W2) + (w >> 1);
                if (pr0     < H2) pp[pr0 * W2]       = o0;
                if (pr0 + 1 < H2) pp[(pr0 + 1) * W2] = o1;
            }
        }
    }
}

// ---------------- bilinear x2 upsample, align_corners=True ----------------
template <int N>
__global__ __launch_bounds__(256) void upsample2(
    const float* __restrict__ in, float* __restrict__ out, int BC)
{
    constexpr int M = 2 * N;
    const int idx = blockIdx.x * 256 + threadIdx.x;
    const int total = BC * M * M;
    if (idx >= total) return;
    const int x = idx % M;
    int tmp = idx / M;
    const int y = tmp % M;
    const int bc = tmp / M;
    const float scale = (float)((double)(N - 1) / (double)(M - 1));
    const float cy = (float)y * scale;
    const float cx = (float)x * scale;
    const int iy0 = (int)floorf(cy);
    const int ix0 = (int)floorf(cx);
    const int iy1 = min(iy0 + 1, N - 1);
    const int ix1 = min(ix0 + 1, N - 1);
    const float wy = cy - (float)iy0;
    const float wx = cx - (float)ix0;
    const float* p = in + (size_t)bc * N * N;
    const float v00 = p[iy0 * N + ix0], v01 = p[iy0 * N + ix1];
    const float v10 = p[iy1 * N + ix0], v11 = p[iy1 * N + ix1];
    const float a0 = v00 * (1.0f - wy) + v10 * wy;
    const float a1 = v01 * (1.0f - wy) + v11 * wy;
    out[idx] = a0 * (1.0f - wx) + a1 * wx;
}

// ---------------- final 1x1 conv (float4) ----------------
__global__ __launch_bounds__(256) void final1x1(
    const float* __restrict__ h, const float* __restrict__ wl,
    const float* __restrict__ bl, float* __restrict__ out)
{
    const int idx = blockIdx.x * 256 + threadIdx.x;
    const int total = BATCH * 196;
    if (idx >= total) return;
    const int s4 = idx % 196;
    const int b = idx / 196;
    const float b0 = bl[0];
    float4 acc = {b0, b0, b0, b0};
    #pragma unroll
    for (int c = 0; c < 10; ++c) {
        const float wv = wl[c];
        const float4 v = ld4(h + ((size_t)b * 10 + c) * 784 + s4 * 4);
        acc.x = fmaf(v.x, wv, acc.x); acc.y = fmaf(v.y, wv, acc.y);
        acc.z = fmaf(v.z, wv, acc.z); acc.w = fmaf(v.w, wv, acc.w);
    }
    ((float4*)out)[idx] = acc;
}

// ---------------------------------------------------------------------------
extern "C" void kernel_launch(void* const* d_in, const int* in_sizes, int n_in,
                              void* d_out, int out_size, void* d_ws, size_t ws_size,
                              hipStream_t stream)
{
    const float* x = (const float*)d_in[0];
    const float* cw[5]; const float* cb[5]; const float* gw[5]; const float* gb[5];
    const float* nw[5]; const float* nb[5]; const float* epsv[5];
    for (int l = 0; l < 5; ++l) {
        cw[l]   = (const float*)d_in[1 + 7 * l + 0];
        cb[l]   = (const float*)d_in[1 + 7 * l + 1];
        gw[l]   = (const float*)d_in[1 + 7 * l + 2];
        gb[l]   = (const float*)d_in[1 + 7 * l + 3];
        nw[l]   = (const float*)d_in[1 + 7 * l + 4];
        nb[l]   = (const float*)d_in[1 + 7 * l + 5];
        epsv[l] = (const float*)d_in[1 + 7 * l + 6];
    }
    const float* wlast = (const float*)d_in[36];
    const float* blast = (const float*)d_in[37];
    const int*   kp    = (const int*)d_in[38];
    float* out = (float*)d_out;
    float* ws  = (float*)d_ws;

    float* conv1 = ws + O_CONV1;
    float* xpad  = ws + O_XPAD;
    float* p1    = ws + O_P1;
    float* conv2 = ws + O_CONV2;
    float* p2    = ws + O_P2;
    float* conv3 = ws + O_CONV3;
    float* up3   = ws + O_UP3;
    float* m4    = ws + O_M4;
    float* up4   = ws + O_UP4;
    float* m5    = ws + O_M5;
    float* graw[5]; float* gate[5];
    for (int l = 0; l < 5; ++l) {
        graw[l] = ws + O_GRAW + (size_t)l * BATCH * 4;
        gate[l] = ws + O_GATE + (size_t)l * BATCH * 4;
    }
    unsigned* ctr = (unsigned*)(ws + O_CTR);

    // zero the 5 last-block counters; padded input copy for conv1 taps
    hipMemsetAsync(ctr, 0, 5 * sizeof(unsigned), stream);
    hipMemcpyAsync(xpad, x, (size_t)BATCH * 784 * sizeof(float),
                   hipMemcpyDeviceToDevice, stream);

    #define CDIV(a) (((a) + 255) / 256)
    const int gq  = 784 * 5;            // q4 grids (L1, L5)
    const int g2  = pb4(14, 14) * 5;
    const int g3  = pb4(7, 7)   * 10;
    const int g4  = pb4(14, 14) * 5;
    const int GB2 = BATCH / 2;

    // ---- layer 1
    gate_block_v4<784, 0><<<GB2, 256, 0, stream>>>(
        x, nullptr, gw[0], gb[0], nw[0], nb[0], epsv[0], kp,
        graw[0], gate[0], ctr + 0);
    moe_conv_q4<1, 0, 10, 1><<<gq, 256, 0, stream>>>(
        xpad, nullptr, cw[0], cb[0], gate[0], conv1, p1);

    // ---- layer 2
    gate_block_v4<1960, 0><<<GB2, 256, 0, stream>>>(
        p1, nullptr, gw[1], gb[1], nw[1], nb[1], epsv[1], kp,
        graw[1], gate[1], ctr + 1);
    moe_conv4<10, 0, 10, 14, 14, 1><<<g2, 256, 0, stream>>>(
        p1, nullptr, cw[1], cb[1], gate[1], conv2, p2);

    // ---- layer 3
    gate_block_s<490><<<BATCH, 256, 0, stream>>>(
        p2, gw[2], gb[2], nw[2], nb[2], epsv[2], kp,
        graw[2], gate[2], ctr + 2);
    moe_conv4<10, 0, 20, 7, 7, 0><<<g3, 256, 0, stream>>>(
        p2, nullptr, cw[2], cb[2], gate[2], conv3, nullptr);
    upsample2<7><<<CDIV(BATCH * 20 * 196), 256, 0, stream>>>(conv3, up3, BATCH * 20);

    // ---- layer 4
    gate_block_v4<3920, 1960><<<GB2, 256, 0, stream>>>(
        up3, conv2, gw[3], gb[3], nw[3], nb[3], epsv[3], kp,
        graw[3], gate[3], ctr + 3);
    moe_conv4<20, 10, 10, 14, 14, 0><<<g4, 256, 0, stream>>>(
        up3, conv2, cw[3], cb[3], gate[3], m4, nullptr);
    upsample2<14><<<CDIV(BATCH * 10 * 784), 256, 0, stream>>>(m4, up4, BATCH * 10);

    // ---- layer 5
    gate_block_v4<7840, 7840><<<GB2, 256, 0, stream>>>(
        up4, conv1, gw[4], gb[4], nw[4], nb[4], epsv[4], kp,
        graw[4], gate[4], ctr + 4);
    moe_conv_q4<10, 10, 10, 0><<<gq, 256, 0, stream>>>(
        up4, conv1, cw[4], cb[4], gate[4], m5, nullptr);
    final1x1<<<CDIV(BATCH * 196), 256, 0, stream>>>(m5, wlast, blast, out);
    #undef CDIV
}